// Round 4
// baseline (186.179 us; speedup 1.0000x reference)
//
#include <hip/hip_runtime.h>

#define Nn 325
#define Dd 64
#define Hh 4
#define Ee 2600
#define BT 192
#define ETOT (Ee+Nn)        // 2925
#define TOTAL (BT*Nn)       // 62400
#define NROWS TOTAL
#define XPS 136             // xpS row stride in shorts (272 B = 17 uint4)
#define XP_B (Nn * XPS * 2) // 88400 B — k_proj LDS

// fused-path (fallback) LDS layout
#define COEF_B (ETOT * 8)              // 23400
#define SMEM_BYTES (XP_B + COEF_B + 2600 + 2600 + ((Nn + 1) * 4) + (ETOT * 4) + (Nn * 4))

typedef __attribute__((ext_vector_type(8))) short bf16x8;
typedef __attribute__((ext_vector_type(4))) float f32x4;

static __device__ __forceinline__ short f2bf(float f) {
    union { float f; unsigned u; } v; v.f = f;
    unsigned r = v.u + 0x7fffu + ((v.u >> 16) & 1u);   // RNE (no NaN in data)
    return (short)(r >> 16);
}
static __device__ __forceinline__ float bf_lo(unsigned p) {
    union { unsigned u; float f; } v; v.u = p << 16; return v.f;
}
static __device__ __forceinline__ float bf_hi(unsigned p) {
    union { unsigned u; float f; } v; v.u = p & 0xffff0000u; return v.f;
}

// =====================================================================
// ===================  NEW SPLIT PATH (needs ~34 MB ws)  ==============
// =====================================================================

// ---- Kernel 0n: Wt prearrange (blk 0..63) + CSR build (blk 64) ----
__global__ __launch_bounds__(256) void k_pre_s(
    const float* __restrict__ W, unsigned short* __restrict__ Wt,
    const int* __restrict__ ei, int* __restrict__ offs, int* __restrict__ elist)
{
    const int t = threadIdx.x;
    if (blockIdx.x < 64) {
        const int f = blockIdx.x * 256 + t;             // 0..16383
        const int thr = f >> 6, idx = f & 63;
        const int ct = idx >> 4, kk = (idx >> 3) & 1, j = idx & 7;
        const int w = thr >> 6, lane = thr & 63;
        const int q = lane >> 4, l16 = lane & 15;
        Wt[f] = (unsigned short)f2bf(
            W[(size_t)(kk * 32 + q * 8 + j) * 256 + w * 64 + ct * 16 + l16]);
        return;
    }
    // ---- CSR build (block 64) ----
    __shared__ int cnt[Nn + 1];
    __shared__ int cur[Nn];
    const int lane = t & 63;
    for (int i = t; i <= Nn; i += 256) cnt[i] = 0;
    __syncthreads();
    for (int e = t; e < ETOT; e += 256) {
        int d = (e < Ee) ? ei[Ee + e] : (e - Ee);
        atomicAdd(&cnt[d + 1], 1);
    }
    __syncthreads();
    if (t < 64) {                       // wave-parallel inclusive scan
        int run = 0;
        for (int c = 0; c < 6; ++c) {
            int i = c * 64 + lane;
            int v = (i <= Nn) ? cnt[i] : 0;
            #pragma unroll
            for (int off = 1; off < 64; off <<= 1) {
                int u = __shfl_up(v, off);
                if (lane >= off) v += u;
            }
            v += run;
            if (i <= Nn) cnt[i] = v;
            run = __shfl(v, 63);
        }
    }
    __syncthreads();
    for (int i = t; i <= Nn; i += 256) offs[i] = cnt[i];
    for (int i = t; i < Nn; i += 256) cur[i] = cnt[i];
    __syncthreads();
    for (int e = t; e < ETOT; e += 256) {
        int s, d;
        if (e < Ee) { s = ei[e]; d = ei[Ee + e]; }
        else        { s = e - Ee; d = e - Ee; }
        int slot = atomicAdd(&cur[d], 1);
        elist[slot] = s;
    }
}

// ---- Kernel 1n: per-bt projection -> xpG (bf16) + alphas to global ----
__global__ __launch_bounds__(1024, 4) void k_proj(
    const float* __restrict__ x, const unsigned short* __restrict__ Wt,
    const float* __restrict__ att_src, const float* __restrict__ att_dst,
    unsigned short* __restrict__ xpG, float* __restrict__ asrcG,
    float* __restrict__ adstG)
{
    const int bt   = blockIdx.x;
    const int t    = threadIdx.x;
    const int wv   = t >> 6;
    const int lane = t & 63;
    const int q    = lane >> 4;
    const int l16  = lane & 15;
    const int btN  = bt * Nn;

    extern __shared__ char smem[];
    unsigned short* xpS = (unsigned short*)smem;    // [Nn][XPS]

    const int hh  = wv >> 3;          // head-half within phase (0/1)
    const int rtb = wv & 7;           // row-tile base

    #pragma unroll 2
    for (int p = 0; p < 2; ++p) {
        const int h = p * 2 + hh;     // global head
        bf16x8 bfr[4][2];
        const bf16x8* wtp = (const bf16x8*)(Wt + (size_t)(h * 64 + lane) * 64);
        #pragma unroll
        for (int ct = 0; ct < 4; ++ct) {
            bfr[ct][0] = wtp[ct * 2];
            bfr[ct][1] = wtp[ct * 2 + 1];
        }
        float avs[4], avd[4];
        #pragma unroll
        for (int ct = 0; ct < 4; ++ct) {
            avs[ct] = att_src[h * 64 + ct * 16 + l16];
            avd[ct] = att_dst[h * 64 + ct * 16 + l16];
        }
        if (p) __syncthreads();       // phase-1 writes wait for phase-0 dump reads

        #pragma unroll
        for (int k3 = 0; k3 < 3; ++k3) {
            const int rt = rtb + 8 * k3;
            if (rt > 20) break;       // wave-uniform
            const int na = min(rt * 16 + l16, Nn - 1);
            const float* xr = x + (size_t)(btN + na) * 64;
            bf16x8 afr[2];
            #pragma unroll
            for (int kk = 0; kk < 2; ++kk) {          // inline fp32 -> bf16
                const float4 xa = *(const float4*)(xr + kk * 32 + q * 8);
                const float4 xb = *(const float4*)(xr + kk * 32 + q * 8 + 4);
                bf16x8 fr;
                fr[0] = f2bf(xa.x); fr[1] = f2bf(xa.y); fr[2] = f2bf(xa.z); fr[3] = f2bf(xa.w);
                fr[4] = f2bf(xb.x); fr[5] = f2bf(xb.y); fr[6] = f2bf(xb.z); fr[7] = f2bf(xb.w);
                afr[kk] = fr;
            }
            f32x4 acc[4];
            #pragma unroll
            for (int ct = 0; ct < 4; ++ct) {
                acc[ct] = (f32x4){0.f, 0.f, 0.f, 0.f};
                acc[ct] = __builtin_amdgcn_mfma_f32_16x16x32_bf16(afr[0], bfr[ct][0], acc[ct], 0, 0, 0);
                acc[ct] = __builtin_amdgcn_mfma_f32_16x16x32_bf16(afr[1], bfr[ct][1], acc[ct], 0, 0, 0);
            }
            // C/D: col = l16 (tile ct), row = q*4 + r
            #pragma unroll
            for (int r = 0; r < 4; ++r) {
                const int n = rt * 16 + q * 4 + r;
                float ps = 0.f, pd = 0.f;
                #pragma unroll
                for (int ct = 0; ct < 4; ++ct) {
                    ps = fmaf(acc[ct][r], avs[ct], ps);
                    pd = fmaf(acc[ct][r], avd[ct], pd);
                }
                #pragma unroll
                for (int off = 1; off <= 8; off <<= 1) {
                    ps += __shfl_xor(ps, off);
                    pd += __shfl_xor(pd, off);
                }
                if (l16 == 0 && n < Nn) {
                    asrcG[(btN + n) * 4 + h] = ps;
                    adstG[(btN + n) * 4 + h] = pd;
                }
                if (n < Nn) {
                    #pragma unroll
                    for (int ct = 0; ct < 4; ++ct)
                        xpS[n * XPS + (ct * 16 + l16) * 2 + hh] =
                            (unsigned short)f2bf(acc[ct][r]);
                }
            }
        }
        __syncthreads();
        // ---- dump phase-p xp (256 B per row per phase) ----
        const uint4* src = (const uint4*)xpS;
        uint4*       dst = (uint4*)xpG;
        for (int i = t; i < Nn * 16; i += 1024) {
            const int row = i >> 4, c16 = i & 15;
            dst[(size_t)(btN + row) * 32 + p * 16 + c16] = src[row * 17 + c16];
        }
    }
}

// ---- Kernel 2n: softmax + gather + epilogue; one wave per (bt,node) ----
#define GBLK 1536
#define WPT  11     // ceil(62400 / (1536*4))
__global__ __launch_bounds__(256, 4) void k_gather(
    const unsigned short* __restrict__ xpG, const float* __restrict__ asrcG,
    const float* __restrict__ adstG, const int* __restrict__ offs,
    const int* __restrict__ elist, const float* __restrict__ x,
    const float* __restrict__ bias, const float* __restrict__ gamma,
    const float* __restrict__ beta, float* __restrict__ out)
{
    __shared__ float coefL[4][48][4];
    __shared__ int   jLs[4][48];
    const int wv   = threadIdx.x >> 6;
    const int lane = threadIdx.x & 63;
    const int l16  = lane & 15;
    const int h    = lane >> 4;        // softmax-phase head
    const int half = lane >> 5;        // MAC-phase head-pair
    const int d0   = (lane & 31) * 2;  // MAC-phase dim pair
    const unsigned laneoff = (unsigned)(half * 256 + (lane & 31) * 8);

    // XCD-aware bijective swizzle: 1536 = 8 * 192
    const int bsw = (blockIdx.x & 7) * 192 + (blockIdx.x >> 3);
    const int gw  = bsw * 4 + wv;
    const int u0  = gw * WPT;
    const int uE  = min(u0 + WPT, TOTAL);

    // loop-invariant epilogue params
    const float2 bi = *(const float2*)(bias + d0);
    const float2 ga = *(const float2*)(gamma + d0);
    const float2 be = *(const float2*)(beta + d0);

    for (int u = u0; u < uE; ++u) {
        const int bt  = u / Nn;
        const int n   = u - bt * Nn;
        const int btN = bt * Nn;

        // ---------- softmax: 16 lanes x 4 heads ----------
        const int o0 = offs[n];
        int deg = offs[n + 1] - o0;
        deg = min(deg, 48);
        const int nch = (deg + 15) >> 4;   // 1..3
        const float adv = adstG[(btN + n) * 4 + h];
        float ex[3]; int jreg[3];
        float m = -3e38f;
        #pragma unroll
        for (int r = 0; r < 3; ++r) {
            float a = -3e38f;
            if (r < nch) {
                const int e = r * 16 + l16;
                const int j = elist[o0 + min(e, deg - 1)];
                jreg[r] = j;
                if (e < deg) {
                    const float av = asrcG[(btN + j) * 4 + h];
                    a = av + adv;
                    a = (a >= 0.f) ? a : 0.2f * a;
                }
            }
            ex[r] = a;
            m = fmaxf(m, a);
        }
        #pragma unroll
        for (int off = 1; off <= 8; off <<= 1)
            m = fmaxf(m, __shfl_xor(m, off));
        float s = 0.f;
        #pragma unroll
        for (int r = 0; r < 3; ++r) if (r < nch) {
            ex[r] = __expf(ex[r] - m);     // invalid lanes: exp(-huge) -> 0
            s += ex[r];
        }
        #pragma unroll
        for (int off = 1; off <= 8; off <<= 1)
            s += __shfl_xor(s, off);
        const float inv = 1.f / (s + 1e-16f);
        #pragma unroll
        for (int r = 0; r < 3; ++r) if (r < nch) {
            const int e = r * 16 + l16;
            if (e < deg) {
                coefL[wv][e][h] = ex[r] * inv;
                if (h == 0) jLs[wv][e] = jreg[r];
            }
        }
        // same-wave LDS write->read: per-wave DS ordering suffices (no barrier)

        // ---------- gather MAC: 64 lanes = (head-pair, dim-pair); 8 edges in flight ----------
        float a00 = 0.f, a01 = 0.f, a10 = 0.f, a11 = 0.f;
        for (int eb = 0; eb < deg; eb += 8) {
            const int ne = min(deg - eb, 8);   // wave-uniform
            int jv[8];
            #pragma unroll
            for (int k = 0; k < 8; ++k) if (k < ne) jv[k] = jLs[wv][eb + k];
            float2 cc[8]; uint2 rr[8];
            #pragma unroll
            for (int k = 0; k < 8; ++k) if (k < ne) {
                cc[k] = *(const float2*)(&coefL[wv][eb + k][half * 2]);
                const unsigned off = ((unsigned)(btN + jv[k]) << 9) + laneoff;
                rr[k] = *(const uint2*)((const char*)xpG + off);
            }
            #pragma unroll
            for (int k = 0; k < 8; ++k) if (k < ne) {
                a00 = fmaf(cc[k].x, bf_lo(rr[k].x), a00);
                a01 = fmaf(cc[k].y, bf_hi(rr[k].x), a01);
                a10 = fmaf(cc[k].x, bf_lo(rr[k].y), a10);
                a11 = fmaf(cc[k].y, bf_hi(rr[k].y), a11);
            }
        }

        // ---------- epilogue: head mean + bias + residual + LayerNorm ----------
        float t0 = a00 + a01, t1 = a10 + a11;
        t0 += __shfl_xor(t0, 32);      // + other head pair
        t1 += __shfl_xor(t1, 32);
        const float2 xv = *(const float2*)(x + (size_t)u * 64 + d0);
        const float y0 = xv.x + t0 * 0.25f + bi.x;
        const float y1 = xv.y + t1 * 0.25f + bi.y;
        float s1 = y0 + y1;
        float s2 = y0 * y0 + y1 * y1;
        #pragma unroll
        for (int off = 1; off <= 16; off <<= 1) {   // 32-lane reduce (within half)
            s1 += __shfl_xor(s1, off);
            s2 += __shfl_xor(s2, off);
        }
        const float mu  = s1 * (1.f / 64.f);
        const float var = s2 * (1.f / 64.f) - mu * mu;
        const float rs  = rsqrtf(var + 1e-5f);
        if (lane < 32) {
            float2 o;
            o.x = (y0 - mu) * rs * ga.x + be.x;
            o.y = (y1 - mu) * rs * ga.y + be.y;
            *(float2*)(out + (size_t)u * 64 + d0) = o;
        }
    }
}

// =====================================================================
// ============  FALLBACK: verbatim R0 two-kernel path  ================
// =====================================================================

__global__ __launch_bounds__(256) void k_pre_f(
    const float* __restrict__ W, unsigned short* __restrict__ Wt,
    const int* __restrict__ ei, int* __restrict__ offs, int* __restrict__ elist,
    int* __restrict__ perm, const float* __restrict__ x,
    unsigned short* __restrict__ xbf)
{
    const int t = threadIdx.x;
    if (blockIdx.x < 64) {
        const int f = blockIdx.x * 256 + t;
        const int thr = f >> 6, idx = f & 63;
        const int ct = idx >> 4, kk = (idx >> 3) & 1, j = idx & 7;
        const int w = thr >> 6, lane = thr & 63;
        const int q = lane >> 4, l16 = lane & 15;
        Wt[f] = (unsigned short)f2bf(
            W[(size_t)(kk * 32 + q * 8 + j) * 256 + w * 64 + ct * 16 + l16]);
        return;
    }
    if (blockIdx.x >= 65) {
        const int bx = blockIdx.x - 65;
        #pragma unroll
        for (int k = 0; k < 8; ++k) {
            const int idx = bx * 2048 + k * 256 + t;
            if (idx < (NROWS * Dd) / 4) {
                float4 v = ((const float4*)x)[idx];
                ushort4 o;
                o.x = (unsigned short)f2bf(v.x);
                o.y = (unsigned short)f2bf(v.y);
                o.z = (unsigned short)f2bf(v.z);
                o.w = (unsigned short)f2bf(v.w);
                ((ushort4*)xbf)[idx] = o;
            }
        }
        return;
    }
    __shared__ int cnt[Nn + 1];
    __shared__ int cur[Nn];
    __shared__ int dh[64];
    __shared__ int startS[64];
    const int lane = t & 63;
    for (int i = t; i <= Nn; i += 256) cnt[i] = 0;
    if (t < 64) dh[t] = 0;
    __syncthreads();
    for (int e = t; e < ETOT; e += 256) {
        int d = (e < Ee) ? ei[Ee + e] : (e - Ee);
        atomicAdd(&cnt[d + 1], 1);
    }
    __syncthreads();
    if (t < 64) {
        int run = 0;
        for (int c = 0; c < 6; ++c) {
            int i = c * 64 + lane;
            int v = (i <= Nn) ? cnt[i] : 0;
            #pragma unroll
            for (int off = 1; off < 64; off <<= 1) {
                int u = __shfl_up(v, off);
                if (lane >= off) v += u;
            }
            v += run;
            if (i <= Nn) cnt[i] = v;
            run = __shfl(v, 63);
        }
    }
    __syncthreads();
    for (int i = t; i <= Nn; i += 256) offs[i] = cnt[i];
    for (int i = t; i < Nn; i += 256) cur[i] = cnt[i];
    for (int n = t; n < Nn; n += 256)
        atomicAdd(&dh[min(cnt[n + 1] - cnt[n], 63)], 1);
    __syncthreads();
    if (t < 64) {
        int v = dh[63 - lane];
        int inc = v;
        #pragma unroll
        for (int off = 1; off < 64; off <<= 1) {
            int u = __shfl_up(inc, off);
            if (lane >= off) inc += u;
        }
        startS[63 - lane] = inc - v;
    }
    __syncthreads();
    for (int e = t; e < ETOT; e += 256) {
        int s, d;
        if (e < Ee) { s = ei[e]; d = ei[Ee + e]; }
        else        { s = e - Ee; d = e - Ee; }
        int slot = atomicAdd(&cur[d], 1);
        elist[slot] = s;
    }
    for (int n = t; n < Nn; n += 256) {
        int slot = atomicAdd(&startS[min(cnt[n + 1] - cnt[n], 63)], 1);
        perm[slot] = n;
    }
}

__global__ __launch_bounds__(1024, 4) void k_fused(
    const float* __restrict__ x, const unsigned short* __restrict__ xbf,
    const unsigned short* __restrict__ Wt,
    const float* __restrict__ att_src, const float* __restrict__ att_dst,
    const int* __restrict__ offs, const int* __restrict__ elist,
    const int* __restrict__ perm,
    const float* __restrict__ bias, const float* __restrict__ gamma,
    const float* __restrict__ beta, float* __restrict__ out)
{
    const int bt   = blockIdx.x;
    const int t    = threadIdx.x;
    const int wv   = t >> 6;
    const int lane = t & 63;
    const int q    = lane >> 4;
    const int l16  = lane & 15;
    const int btN  = bt * Nn;

    extern __shared__ char smem[];
    unsigned short* xpS   = (unsigned short*)smem;
    float2*         coefS = (float2*)(smem + XP_B);
    float*          asrcS = (float*)(smem + XP_B + COEF_B);
    float*          adstS = asrcS + 2 * Nn;
    int*            offsS = (int*)(adstS + 2 * Nn);
    int*            elistS= offsS + (Nn + 1);
    int*            permS = elistS + ETOT;

    for (int i = t; i < ETOT; i += 1024) elistS[i] = elist[i];
    for (int i = t; i <= Nn; i += 1024) offsS[i] = offs[i];
    for (int i = t; i < Nn; i += 1024) permS[i] = perm[i];

    float accO[6][4];
    #pragma unroll
    for (int i = 0; i < 6; ++i)
        accO[i][0] = accO[i][1] = accO[i][2] = accO[i][3] = 0.f;

    const int hh  = wv >> 3;
    const int rtb = wv & 7;
    const int g   = wv * 4 + q;

    #pragma unroll 2
    for (int p = 0; p < 2; ++p) {
        const int h = p * 2 + hh;
        bf16x8 bfr[4][2];
        const bf16x8* wtp = (const bf16x8*)(Wt + (size_t)(h * 64 + lane) * 64);
        #pragma unroll
        for (int ct = 0; ct < 4; ++ct) {
            bfr[ct][0] = wtp[ct * 2];
            bfr[ct][1] = wtp[ct * 2 + 1];
        }
        float avs[4], avd[4];
        #pragma unroll
        for (int ct = 0; ct < 4; ++ct) {
            avs[ct] = att_src[h * 64 + ct * 16 + l16];
            avd[ct] = att_dst[h * 64 + ct * 16 + l16];
        }
        if (p) __syncthreads();

        #pragma unroll
        for (int k3 = 0; k3 < 3; ++k3) {
            const int rt = rtb + 8 * k3;
            if (rt > 20) break;
            const int na = min(rt * 16 + l16, Nn - 1);
            bf16x8 afr[2];
            #pragma unroll
            for (int kk = 0; kk < 2; ++kk)
                afr[kk] = *(const bf16x8*)(xbf + (size_t)(btN + na) * 64 + kk * 32 + q * 8);
            f32x4 acc[4];
            #pragma unroll
            for (int ct = 0; ct < 4; ++ct) {
                acc[ct] = (f32x4){0.f, 0.f, 0.f, 0.f};
                acc[ct] = __builtin_amdgcn_mfma_f32_16x16x32_bf16(afr[0], bfr[ct][0], acc[ct], 0, 0, 0);
                acc[ct] = __builtin_amdgcn_mfma_f32_16x16x32_bf16(afr[1], bfr[ct][1], acc[ct], 0, 0, 0);
            }
            #pragma unroll
            for (int r = 0; r < 4; ++r) {
                const int n = rt * 16 + q * 4 + r;
                float ps = 0.f, pd = 0.f;
                #pragma unroll
                for (int ct = 0; ct < 4; ++ct) {
                    ps = fmaf(acc[ct][r], avs[ct], ps);
                    pd = fmaf(acc[ct][r], avd[ct], pd);
                }
                #pragma unroll
                for (int off = 1; off <= 8; off <<= 1) {
                    ps += __shfl_xor(ps, off);
                    pd += __shfl_xor(pd, off);
                }
                if (l16 == 0 && n < Nn) {
                    asrcS[n * 2 + hh] = ps;
                    adstS[n * 2 + hh] = pd;
                }
                if (n < Nn) {
                    #pragma unroll
                    for (int ct = 0; ct < 4; ++ct)
                        xpS[n * XPS + (ct * 16 + l16) * 2 + hh] =
                            (unsigned short)f2bf(acc[ct][r]);
                }
            }
        }
        __syncthreads();

        #pragma unroll
        for (int it = 0; it < 6; ++it) {
            const int rk = it * 64 + g;
            if (rk >= Nn) continue;
            const int n = permS[rk];
            const int o0 = offsS[n];
            int deg = offsS[n + 1] - o0;
            deg = min(deg, 48);
            const float adn0 = adstS[n * 2], adn1 = adstS[n * 2 + 1];
            float ex0[3], ex1[3];
            float m0 = -3e38f, m1 = -3e38f;
            #pragma unroll
            for (int r = 0; r < 3; ++r) {
                float a0 = -3e38f, a1 = -3e38f;
                if (r * 16 < deg) {
                    const int e = r * 16 + l16;
                    if (e < deg) {
                        const int j = elistS[o0 + e];
                        const float2 as = *(const float2*)(asrcS + j * 2);
                        a0 = as.x + adn0; a1 = as.y + adn1;
                    }
                }
                a0 = (a0 >= 0.f) ? a0 : 0.2f * a0;
                a1 = (a1 >= 0.f) ? a1 : 0.2f * a1;
                ex0[r] = a0; ex1[r] = a1;
                m0 = fmaxf(m0, a0); m1 = fmaxf(m1, a1);
            }
            #pragma unroll
            for (int off = 1; off <= 8; off <<= 1) {
                m0 = fmaxf(m0, __shfl_xor(m0, off));
                m1 = fmaxf(m1, __shfl_xor(m1, off));
            }
            float s0 = 0.f, s1 = 0.f;
            #pragma unroll
            for (int r = 0; r < 3; ++r) if (r * 16 < deg) {
                ex0[r] = __expf(ex0[r] - m0); s0 += ex0[r];
                ex1[r] = __expf(ex1[r] - m1); s1 += ex1[r];
            }
            #pragma unroll
            for (int off = 1; off <= 8; off <<= 1) {
                s0 += __shfl_xor(s0, off);
                s1 += __shfl_xor(s1, off);
            }
            const float i0 = 1.f / (s0 + 1e-16f);
            const float i1 = 1.f / (s1 + 1e-16f);
            #pragma unroll
            for (int r = 0; r < 3; ++r) if (r * 16 < deg) {
                const int e = r * 16 + l16;
                if (e < deg) coefS[o0 + e] = make_float2(ex0[r] * i0, ex1[r] * i1);
            }

            float f0 = 0.f, f1 = 0.f, f2v = 0.f, f3 = 0.f;
            int e2 = 0;
            for (; e2 + 4 <= deg; e2 += 4) {
                const int j0 = elistS[o0 + e2],     j1 = elistS[o0 + e2 + 1];
                const int j2 = elistS[o0 + e2 + 2], j3 = elistS[o0 + e2 + 3];
                const float2 c0 = coefS[o0 + e2],     c1 = coefS[o0 + e2 + 1];
                const float2 c2 = coefS[o0 + e2 + 2], c3 = coefS[o0 + e2 + 3];
                const uint4 r0 = *(const uint4*)((const char*)xpS + j0 * (XPS * 2) + l16 * 16);
                const uint4 r1 = *(const uint4*)((const char*)xpS + j1 * (XPS * 2) + l16 * 16);
                const uint4 r2 = *(const uint4*)((const char*)xpS + j2 * (XPS * 2) + l16 * 16);
                const uint4 r3 = *(const uint4*)((const char*)xpS + j3 * (XPS * 2) + l16 * 16);
                f0  = fmaf(c0.x, bf_lo(r0.x), f0);  f0  = fmaf(c0.y, bf_hi(r0.x), f0);
                f1  = fmaf(c0.x, bf_lo(r0.y), f1);  f1  = fmaf(c0.y, bf_hi(r0.y), f1);
                f2v = fmaf(c0.x, bf_lo(r0.z), f2v); f2v = fmaf(c0.y, bf_hi(r0.z), f2v);
                f3  = fmaf(c0.x, bf_lo(r0.w), f3);  f3  = fmaf(c0.y, bf_hi(r0.w), f3);
                f0  = fmaf(c1.x, bf_lo(r1.x), f0);  f0  = fmaf(c1.y, bf_hi(r1.x), f0);
                f1  = fmaf(c1.x, bf_lo(r1.y), f1);  f1  = fmaf(c1.y, bf_hi(r1.y), f1);
                f2v = fmaf(c1.x, bf_lo(r1.z), f2v); f2v = fmaf(c1.y, bf_hi(r1.z), f2v);
                f3  = fmaf(c1.x, bf_lo(r1.w), f3);  f3  = fmaf(c1.y, bf_hi(r1.w), f3);
                f0  = fmaf(c2.x, bf_lo(r2.x), f0);  f0  = fmaf(c2.y, bf_hi(r2.x), f0);
                f1  = fmaf(c2.x, bf_lo(r2.y), f1);  f1  = fmaf(c2.y, bf_hi(r2.y), f1);
                f2v = fmaf(c2.x, bf_lo(r2.z), f2v); f2v = fmaf(c2.y, bf_hi(r2.z), f2v);
                f3  = fmaf(c2.x, bf_lo(r2.w), f3);  f3  = fmaf(c2.y, bf_hi(r2.w), f3);
                f0  = fmaf(c3.x, bf_lo(r3.x), f0);  f0  = fmaf(c3.y, bf_hi(r3.x), f0);
                f1  = fmaf(c3.x, bf_lo(r3.y), f1);  f1  = fmaf(c3.y, bf_hi(r3.y), f1);
                f2v = fmaf(c3.x, bf_lo(r3.z), f2v); f2v = fmaf(c3.y, bf_hi(r3.z), f2v);
                f3  = fmaf(c3.x, bf_lo(r3.w), f3);  f3  = fmaf(c3.y, bf_hi(r3.w), f3);
            }
            for (; e2 < deg; ++e2) {
                const int ja = elistS[o0 + e2];
                const float2 ca = coefS[o0 + e2];
                const uint4 ra = *(const uint4*)((const char*)xpS + ja * (XPS * 2) + l16 * 16);
                f0  = fmaf(ca.x, bf_lo(ra.x), f0);  f0  = fmaf(ca.y, bf_hi(ra.x), f0);
                f1  = fmaf(ca.x, bf_lo(ra.y), f1);  f1  = fmaf(ca.y, bf_hi(ra.y), f1);
                f2v = fmaf(ca.x, bf_lo(ra.z), f2v); f2v = fmaf(ca.y, bf_hi(ra.z), f2v);
                f3  = fmaf(ca.x, bf_lo(ra.w), f3);  f3  = fmaf(ca.y, bf_hi(ra.w), f3);
            }
            accO[it][0] += f0; accO[it][1] += f1;
            accO[it][2] += f2v; accO[it][3] += f3;
        }
    }

    const int f4 = l16 * 4;
    const float4 ga = *(const float4*)(gamma + f4);
    const float4 be = *(const float4*)(beta + f4);
    const float4 bi = *(const float4*)(bias + f4);
    #pragma unroll
    for (int it = 0; it < 6; ++it) {
        const int rk = it * 64 + g;
        if (rk >= Nn) continue;
        const int n = permS[rk];
        const float4 xv = *(const float4*)(x + (size_t)(btN + n) * 64 + f4);
        const float y0 = xv.x + accO[it][0] * 0.25f + bi.x;
        const float y1 = xv.y + accO[it][1] * 0.25f + bi.y;
        const float y2 = xv.z + accO[it][2] * 0.25f + bi.z;
        const float y3 = xv.w + accO[it][3] * 0.25f + bi.w;
        float s1 = y0 + y1 + y2 + y3;
        float s2 = y0*y0 + y1*y1 + y2*y2 + y3*y3;
        #pragma unroll
        for (int off = 1; off <= 8; off <<= 1) {
            s1 += __shfl_xor(s1, off);
            s2 += __shfl_xor(s2, off);
        }
        const float mu  = s1 * (1.f / 64.f);
        const float var = s2 * (1.f / 64.f) - mu * mu;
        const float rr  = rsqrtf(var + 1e-5f);
        float4 o;
        o.x = (y0 - mu) * rr * ga.x + be.x;
        o.y = (y1 - mu) * rr * ga.y + be.y;
        o.z = (y2 - mu) * rr * ga.z + be.z;
        o.w = (y3 - mu) * rr * ga.w + be.w;
        *(float4*)(out + (size_t)(btN + n) * 64 + f4) = o;
    }
}

// =====================================================================

extern "C" void kernel_launch(void* const* d_in, const int* in_sizes, int n_in,
                              void* d_out, int out_size, void* d_ws, size_t ws_size,
                              hipStream_t stream)
{
    const float* x       = (const float*)d_in[0];
    const float* W       = (const float*)d_in[1];
    const float* att_src = (const float*)d_in[2];
    const float* att_dst = (const float*)d_in[3];
    const float* bias    = (const float*)d_in[4];
    const float* gamma   = (const float*)d_in[5];
    const float* beta    = (const float*)d_in[6];
    const int*   ei      = (const int*)d_in[7];
    float* out = (float*)d_out;
    (void)in_sizes; (void)n_in; (void)out_size;

    // ---- new split path workspace need ----
    const size_t hdr    = (32768 + (326 + 2925) * 4 + 15) & ~(size_t)15;  // Wt + offs + elist
    const size_t asz    = (size_t)TOTAL * 4 * 4;                          // asrcG bytes
    const size_t xpsz   = (size_t)TOTAL * 256 * 2;                        // xpG bytes
    const size_t need   = hdr + 2 * asz + xpsz;                           // ~34.0 MB

    if (ws_size >= need) {
        unsigned short* Wt    = (unsigned short*)d_ws;
        int*            offs  = (int*)(Wt + 16384);
        int*            elist = offs + 326;
        char*           base  = (char*)d_ws + hdr;
        float*          asrcG = (float*)base;
        float*          adstG = asrcG + (size_t)TOTAL * 4;
        unsigned short* xpG   = (unsigned short*)(adstG + (size_t)TOTAL * 4);

        hipFuncSetAttribute((const void*)k_proj,
                            hipFuncAttributeMaxDynamicSharedMemorySize, XP_B);

        hipLaunchKernelGGL(k_pre_s, dim3(65), dim3(256), 0, stream, W, Wt, ei, offs, elist);
        hipLaunchKernelGGL(k_proj, dim3(BT), dim3(1024), XP_B, stream,
                           x, Wt, att_src, att_dst, xpG, asrcG, adstG);
        hipLaunchKernelGGL(k_gather, dim3(GBLK), dim3(256), 0, stream,
                           xpG, asrcG, adstG, offs, elist, x, bias, gamma, beta, out);
    } else {
        // ---- fallback: verbatim R0 two-kernel path (~8.03 MB ws) ----
        unsigned short* Wt  = (unsigned short*)d_ws;           // 16384 bf16
        unsigned short* xbf = Wt + 16384;                      // NROWS*64 bf16
        int* offs  = (int*)(xbf + (size_t)NROWS * Dd);         // Nn+1
        int* elist = offs + (Nn + 1);                          // ETOT
        int* perm  = elist + ETOT;                             // Nn

        hipFuncSetAttribute((const void*)k_fused,
                            hipFuncAttributeMaxDynamicSharedMemorySize, SMEM_BYTES);

        hipLaunchKernelGGL(k_pre_f, dim3(65 + 488), dim3(256), 0, stream,
                           W, Wt, ei, offs, elist, perm, x, xbf);
        hipLaunchKernelGGL(k_fused, dim3(BT), dim3(1024), SMEM_BYTES, stream,
                           x, xbf, Wt, att_src, att_dst, offs, elist, perm,
                           bias, gamma, beta, out);
    }
}